// Round 9
// baseline (302.978 us; speedup 1.0000x reference)
//
#include <hip/hip_runtime.h>

#define D 128
#define NEG_SLOPE 0.2f
#define SLOTS 20        // fixed CSR slots per node; P(deg>20)~3e-5 -> overflow list
#define OVF_CAP 4096

using v8f16 = __attribute__((ext_vector_type(8))) _Float16;
using v2h   = __attribute__((ext_vector_type(2))) _Float16;
using f32x4 = __attribute__((ext_vector_type(4))) float;

// ---------------- prep: zero cnt/ovf_n + convert W1/W2 -> f16 transposed ----------------

__global__ __launch_bounds__(256) void prep_kernel(const float* __restrict__ W1,
        const float* __restrict__ W2, _Float16* __restrict__ Wt1,
        _Float16* __restrict__ Wt2, int* __restrict__ cnt,
        int* __restrict__ ovf_n, int n) {
    int t = blockIdx.x * 256 + threadIdx.x;   // 0..32767
    if (t == 0) *ovf_n = 0;
    for (int i = t; i < n; i += 32768) cnt[i] = 0;
    int which = t >> 14;
    int idx = t & 16383;
    int k = idx & (D - 1);
    int c = idx >> 7;
    const float* W = which ? W2 : W1;
    _Float16* Wt = which ? Wt2 : Wt1;
    Wt[(size_t)c * D + k] = (_Float16)W[(size_t)k * D + c];
}

// ---------------- GEMM body (shared by mega1 and gemm2) ----------------

// H[n x 128](f16) = X @ W via mfma_f32_16x16x32_f16. No LDS, no barriers.
// Fused epilogue from fp32 accumulators: hs = H·a_src, hd = H·a_dst.
template<bool F16IN>
__device__ __forceinline__ void gemm_body(int bid, const void* __restrict__ Xv,
        const _Float16* __restrict__ Wt, const float* __restrict__ a_src,
        const float* __restrict__ a_dst, _Float16* __restrict__ H,
        float* __restrict__ hs, float* __restrict__ hd, int n) {
    const int lane = threadIdx.x & 63;
    const int wave = threadIdx.x >> 6;
    const int gl = lane & 15;
    const int q = lane >> 4;
    const int row0 = bid * 64 + wave * 16;

    int arow = row0 + gl;
    if (arow >= n) arow = n - 1;   // clamped load; stores are guarded below

    f32x4 acc[8];
    #pragma unroll
    for (int t = 0; t < 8; ++t) acc[t] = (f32x4){0.f, 0.f, 0.f, 0.f};

    #pragma unroll
    for (int kc = 0; kc < 4; ++kc) {
        v8f16 afr;
        if constexpr (F16IN) {
            const _Float16* Xh = (const _Float16*)Xv;
            afr = *(const v8f16*)&Xh[(size_t)arow * D + kc * 32 + q * 8];
        } else {
            const float* Xf = (const float*)Xv;
            const float* p = &Xf[(size_t)arow * D + kc * 32 + q * 8];
            float4 x0 = *(const float4*)p;
            float4 x1 = *(const float4*)(p + 4);
            afr[0] = (_Float16)x0.x; afr[1] = (_Float16)x0.y;
            afr[2] = (_Float16)x0.z; afr[3] = (_Float16)x0.w;
            afr[4] = (_Float16)x1.x; afr[5] = (_Float16)x1.y;
            afr[6] = (_Float16)x1.z; afr[7] = (_Float16)x1.w;
        }
        #pragma unroll
        for (int t = 0; t < 8; ++t) {
            v8f16 bfr = *(const v8f16*)&Wt[(size_t)(t * 16 + gl) * D + kc * 32 + q * 8];
            acc[t] = __builtin_amdgcn_mfma_f32_16x16x32_f16(afr, bfr, acc[t], 0, 0, 0);
        }
    }

    float asv[8], adv[8];
    #pragma unroll
    for (int t = 0; t < 8; ++t) { asv[t] = a_src[t * 16 + gl]; adv[t] = a_dst[t * 16 + gl]; }

    // C/D layout: col = t*16 + (lane&15), row = row0 + q*4 + reg
    #pragma unroll
    for (int r = 0; r < 4; ++r) {
        int row = row0 + q * 4 + r;
        bool ok = row < n;
        float ps = 0.f, pd = 0.f;
        #pragma unroll
        for (int t = 0; t < 8; ++t) {
            float v = acc[t][r];
            ps = fmaf(v, asv[t], ps);
            pd = fmaf(v, adv[t], pd);
            if (ok) H[(size_t)row * D + t * 16 + gl] = (_Float16)v;
        }
        #pragma unroll
        for (int dlt = 8; dlt > 0; dlt >>= 1) {
            ps += __shfl_down(ps, dlt, 16);
            pd += __shfl_down(pd, dlt, 16);
        }
        if (ok && gl == 0) { hs[row] = ps; hd[row] = pd; }
    }
}

// ---------------- mega1: GEMM1 interleaved with rank+place ----------------
// Even blocks in [0, 2*gb) run GEMM, odd run rank; blocks >= 2*gb run rank.
// Both populations are co-resident from t=0 so the latency-bound atomic pass
// and the memory/MFMA-bound GEMM overlap (requires eb >= gb, true here).
// rank+place writes the fixed-slot CSR directly: csr[d*SLOTS + r] = s.

__global__ __launch_bounds__(256) void mega1_kernel(
        const float* __restrict__ x, const _Float16* __restrict__ Wt1,
        const float* __restrict__ a_src1, const float* __restrict__ a_dst1,
        _Float16* __restrict__ h, float* __restrict__ hs, float* __restrict__ hd,
        const int* __restrict__ ei, int* __restrict__ cnt, int* __restrict__ csr,
        int* __restrict__ ovf_n, int* __restrict__ ovf,
        int gb, int e_in, int n) {
    int b = blockIdx.x;
    int rid;
    if (b < 2 * gb) {
        if ((b & 1) == 0) {
            gemm_body<false>(b >> 1, x, Wt1, a_src1, a_dst1, h, hs, hd, n);
            return;
        }
        rid = b >> 1;
    } else {
        rid = b - gb;
    }
    int e = rid * 256 + threadIdx.x;
    int tot = e_in + n;
    if (e >= tot) return;
    int s, d;
    if (e < e_in) { s = ei[e]; d = ei[e_in + e]; }
    else          { s = e - e_in; d = s; }
    int r = atomicAdd(&cnt[d], 1);
    if (r < SLOTS) {
        csr[d * SLOTS + r] = s;
    } else {
        int ix = atomicAdd(ovf_n, 1);
        if (ix < OVF_CAP) { ovf[2 * ix] = d; ovf[2 * ix + 1] = s; }
    }
}

__global__ __launch_bounds__(256) void gemm2_kernel(
        const _Float16* __restrict__ tb, const _Float16* __restrict__ Wt2,
        const float* __restrict__ a_src2, const float* __restrict__ a_dst2,
        _Float16* __restrict__ h, float* __restrict__ hs, float* __restrict__ hd,
        int n) {
    gemm_body<true>(blockIdx.x, tb, Wt2, a_src2, a_dst2, h, hs, hd, n);
}

// ---------------- aggregate ----------------

__device__ __forceinline__ v2h pack_lo(uint a, uint b) {
    v2h r;
    r.x = __builtin_bit_cast(_Float16, (unsigned short)(a & 0xffffu));
    r.y = __builtin_bit_cast(_Float16, (unsigned short)(b & 0xffffu));
    return r;
}
__device__ __forceinline__ v2h pack_hi(uint a, uint b) {
    v2h r;
    r.x = __builtin_bit_cast(_Float16, (unsigned short)(a >> 16));
    r.y = __builtin_bit_cast(_Float16, (unsigned short)(b >> 16));
    return r;
}
__device__ __forceinline__ float lo_f(uint a) {
    return (float)__builtin_bit_cast(_Float16, (unsigned short)(a & 0xffffu));
}
__device__ __forceinline__ float hi_f(uint a) {
    return (float)__builtin_bit_cast(_Float16, (unsigned short)(a >> 16));
}

// Two nodes per 128-thread block, one wave per node; 12 slots in flight per
// trip (group grp=lane>>4 owns slots j+3*grp..j+3*grp+2; gl=lane&15 owns 16B
// of the 256B f16 row). deg<=SLOTS handled in <=2 trips from the fixed-slot
// CSR; the rare deg>SLOTS nodes additionally scan the tiny overflow list.
template<bool OUT_F16>
__global__ __launch_bounds__(128) void aggregate_kernel(
        const _Float16* __restrict__ h, const float* __restrict__ hs,
        const float* __restrict__ hd, const int* __restrict__ cnt,
        const int* __restrict__ csr, const int* __restrict__ ovf_n,
        const int* __restrict__ ovf, const float* __restrict__ bias,
        float* __restrict__ outf, _Float16* __restrict__ outb, int n) {
    int node = blockIdx.x * 2 + (threadIdx.x >> 6);
    if (node >= n) return;
    int lane = threadIdx.x & 63;
    int grp = lane >> 4;
    int gl = lane & 15;
    int deg = cnt[node];
    int mind = deg < SLOTS ? deg : SLOTS;
    const int base = node * SLOTS;
    float hdn = hd[node];
    const uint* hp = (const uint*)h;   // 2 f16 per uint, row stride 64 uints

    float acc[8] = {0.f, 0.f, 0.f, 0.f, 0.f, 0.f, 0.f, 0.f};
    float z = 0.f;
    for (int j = 0; j < mind; j += 12) {
        int jb = j + 3 * grp;
        bool a0 = jb < mind, a1 = jb + 1 < mind, a2 = jb + 2 < mind;
        int s0 = a0 ? csr[base + jb] : node;
        int s1 = a1 ? csr[base + jb + 1] : node;
        int s2 = a2 ? csr[base + jb + 2] : node;
        float e0 = hs[s0] + hdn;
        float e1 = hs[s1] + hdn;
        float e2 = hs[s2] + hdn;
        e0 = e0 > 0.f ? e0 : NEG_SLOPE * e0;
        e1 = e1 > 0.f ? e1 : NEG_SLOPE * e1;
        e2 = e2 > 0.f ? e2 : NEG_SLOPE * e2;
        float w0 = a0 ? __expf(e0) : 0.f;
        float w1 = a1 ? __expf(e1) : 0.f;
        float w2 = a2 ? __expf(e2) : 0.f;
        uint4 r0 = *(const uint4*)(hp + ((size_t)s0 << 6) + (gl << 2));
        uint4 r1 = *(const uint4*)(hp + ((size_t)s1 << 6) + (gl << 2));
        uint4 r2 = *(const uint4*)(hp + ((size_t)s2 << 6) + (gl << 2));
#if __has_builtin(__builtin_amdgcn_fdot2)
        v2h w01; w01.x = (_Float16)w0; w01.y = (_Float16)w1;
        acc[0] = __builtin_amdgcn_fdot2(pack_lo(r0.x, r1.x), w01, acc[0], false);
        acc[1] = __builtin_amdgcn_fdot2(pack_hi(r0.x, r1.x), w01, acc[1], false);
        acc[2] = __builtin_amdgcn_fdot2(pack_lo(r0.y, r1.y), w01, acc[2], false);
        acc[3] = __builtin_amdgcn_fdot2(pack_hi(r0.y, r1.y), w01, acc[3], false);
        acc[4] = __builtin_amdgcn_fdot2(pack_lo(r0.z, r1.z), w01, acc[4], false);
        acc[5] = __builtin_amdgcn_fdot2(pack_hi(r0.z, r1.z), w01, acc[5], false);
        acc[6] = __builtin_amdgcn_fdot2(pack_lo(r0.w, r1.w), w01, acc[6], false);
        acc[7] = __builtin_amdgcn_fdot2(pack_hi(r0.w, r1.w), w01, acc[7], false);
#else
        acc[0] = fmaf(w0, lo_f(r0.x), acc[0]); acc[1] = fmaf(w0, hi_f(r0.x), acc[1]);
        acc[2] = fmaf(w0, lo_f(r0.y), acc[2]); acc[3] = fmaf(w0, hi_f(r0.y), acc[3]);
        acc[4] = fmaf(w0, lo_f(r0.z), acc[4]); acc[5] = fmaf(w0, hi_f(r0.z), acc[5]);
        acc[6] = fmaf(w0, lo_f(r0.w), acc[6]); acc[7] = fmaf(w0, hi_f(r0.w), acc[7]);
        acc[0] = fmaf(w1, lo_f(r1.x), acc[0]); acc[1] = fmaf(w1, hi_f(r1.x), acc[1]);
        acc[2] = fmaf(w1, lo_f(r1.y), acc[2]); acc[3] = fmaf(w1, hi_f(r1.y), acc[3]);
        acc[4] = fmaf(w1, lo_f(r1.z), acc[4]); acc[5] = fmaf(w1, hi_f(r1.z), acc[5]);
        acc[6] = fmaf(w1, lo_f(r1.w), acc[6]); acc[7] = fmaf(w1, hi_f(r1.w), acc[7]);
#endif
        acc[0] = fmaf(w2, lo_f(r2.x), acc[0]); acc[1] = fmaf(w2, hi_f(r2.x), acc[1]);
        acc[2] = fmaf(w2, lo_f(r2.y), acc[2]); acc[3] = fmaf(w2, hi_f(r2.y), acc[3]);
        acc[4] = fmaf(w2, lo_f(r2.z), acc[4]); acc[5] = fmaf(w2, hi_f(r2.z), acc[5]);
        acc[6] = fmaf(w2, lo_f(r2.w), acc[6]); acc[7] = fmaf(w2, hi_f(r2.w), acc[7]);
        z += w0 + w1 + w2;
    }
    // rare: node overflowed its fixed slots -> scan the tiny overflow list
    if (deg > SLOTS) {
        int m = *ovf_n;
        if (m > OVF_CAP) m = OVF_CAP;
        for (int i = 0; i < m; ++i) {
            int od = ovf[2 * i];
            if (od == node) {
                int os = ovf[2 * i + 1];
                float e = hs[os] + hdn;
                e = e > 0.f ? e : NEG_SLOPE * e;
                float w = __expf(e);
                if (grp == 0) {
                    uint4 r = *(const uint4*)(hp + ((size_t)os << 6) + (gl << 2));
                    acc[0] = fmaf(w, lo_f(r.x), acc[0]); acc[1] = fmaf(w, hi_f(r.x), acc[1]);
                    acc[2] = fmaf(w, lo_f(r.y), acc[2]); acc[3] = fmaf(w, hi_f(r.y), acc[3]);
                    acc[4] = fmaf(w, lo_f(r.z), acc[4]); acc[5] = fmaf(w, hi_f(r.z), acc[5]);
                    acc[6] = fmaf(w, lo_f(r.w), acc[6]); acc[7] = fmaf(w, hi_f(r.w), acc[7]);
                    z += w;
                }
            }
        }
    }
    // combine the 4 slot groups -> lanes 0..15 hold the full row
    #pragma unroll
    for (int dlt = 32; dlt >= 16; dlt >>= 1) {
        #pragma unroll
        for (int k = 0; k < 8; ++k) acc[k] += __shfl_down(acc[k], dlt, 64);
        z += __shfl_down(z, dlt, 64);
    }
    if (lane < 16) {
        float inv = 1.0f / z;   // self-loop guarantees z > 0
        float4 b0 = *(const float4*)&bias[lane * 8];
        float4 b1 = *(const float4*)&bias[lane * 8 + 4];
        float o[8];
        o[0] = acc[0] * inv + b0.x; o[1] = acc[1] * inv + b0.y;
        o[2] = acc[2] * inv + b0.z; o[3] = acc[3] * inv + b0.w;
        o[4] = acc[4] * inv + b1.x; o[5] = acc[5] * inv + b1.y;
        o[6] = acc[6] * inv + b1.z; o[7] = acc[7] * inv + b1.w;
        #pragma unroll
        for (int k = 0; k < 8; ++k) o[k] = o[k] > 0.f ? o[k] : 0.f;
        if constexpr (OUT_F16) {
            alignas(16) _Float16 ob[8];
            #pragma unroll
            for (int k = 0; k < 8; ++k) ob[k] = (_Float16)o[k];
            *(uint4*)&outb[(size_t)node * D + lane * 8] = *(const uint4*)ob;
        } else {
            float* op = outf + (size_t)node * D + lane * 8;
            *(float4*)op = make_float4(o[0], o[1], o[2], o[3]);
            *(float4*)(op + 4) = make_float4(o[4], o[5], o[6], o[7]);
        }
    }
}

// ---------------- Orchestration ----------------

extern "C" void kernel_launch(void* const* d_in, const int* in_sizes, int n_in,
                              void* d_out, int out_size, void* d_ws, size_t ws_size,
                              hipStream_t stream) {
    const float* x      = (const float*)d_in[0];
    const int*   ei     = (const int*)d_in[1];
    const float* W1     = (const float*)d_in[2];
    const float* a_src1 = (const float*)d_in[3];
    const float* a_dst1 = (const float*)d_in[4];
    const float* b1     = (const float*)d_in[5];
    const float* W2     = (const float*)d_in[6];
    const float* a_src2 = (const float*)d_in[7];
    const float* a_dst2 = (const float*)d_in[8];
    const float* b2     = (const float*)d_in[9];

    int n    = in_sizes[0] / D;       // 100000
    int e_in = in_sizes[1] / 2;       // 625000
    int e_tot = e_in + n;             // 725000

    // ws: h(f16) | Wt1 | Wt2 | hs | hd | cnt | ovf_n | ovf | csr  (~33 MB)
    _Float16* h   = (_Float16*)d_ws;
    _Float16* Wt1 = h + (size_t)n * D;
    _Float16* Wt2 = Wt1 + D * D;
    float* hs     = (float*)(Wt2 + D * D);
    float* hd     = hs + n;
    int*   cnt    = (int*)(hd + n);
    int*   ovf_n  = cnt + n;
    int*   ovf    = ovf_n + 1;
    int*   csr    = ovf + 2 * OVF_CAP;
    // layer-1 f16 output lives in d_out's first half (dead before agg2's fp32 write)
    _Float16* tb  = (_Float16*)d_out;

    int eb = (e_tot + 255) / 256;     // 2833
    int nb2 = (n + 1) / 2;
    int gb = (n + 63) / 64;           // 1563 (eb >= gb required by mega1 mapping)

    prep_kernel<<<128, 256, 0, stream>>>(W1, W2, Wt1, Wt2, cnt, ovf_n, n);
    mega1_kernel<<<gb + eb, 256, 0, stream>>>(x, Wt1, a_src1, a_dst1, h, hs, hd,
                                              ei, cnt, csr, ovf_n, ovf, gb, e_in, n);
    aggregate_kernel<true><<<nb2, 128, 0, stream>>>(h, hs, hd, cnt, csr, ovf_n, ovf,
                                                    b1, nullptr, tb, n);
    gemm2_kernel<<<gb, 256, 0, stream>>>(tb, Wt2, a_src2, a_dst2, h, hs, hd, n);
    aggregate_kernel<false><<<nb2, 128, 0, stream>>>(h, hs, hd, cnt, csr, ovf_n, ovf,
                                                     b2, (float*)d_out, nullptr, n);
}

// Round 10
// 280.483 us; speedup vs baseline: 1.0802x; 1.0802x over previous
//
#include <hip/hip_runtime.h>

#define D 128
#define WS (D + 8)      // LDS row stride in f16: 68 words -> 8-round b128 reads (optimal)
#define NEG_SLOPE 0.2f
#define SLOTS 20        // fixed CSR slots per node; P(deg>20)~3e-5 -> overflow list
#define OVF_CAP 4096

using v8f16 = __attribute__((ext_vector_type(8))) _Float16;
using v2h   = __attribute__((ext_vector_type(2))) _Float16;
using f32x4 = __attribute__((ext_vector_type(4))) float;

// ---------------- prep: zero cnt/ovf_n + convert W1/W2 -> f16 transposed ----------------

__global__ __launch_bounds__(256) void prep_kernel(const float* __restrict__ W1,
        const float* __restrict__ W2, _Float16* __restrict__ Wt1,
        _Float16* __restrict__ Wt2, int* __restrict__ cnt,
        int* __restrict__ ovf_n, int n) {
    int t = blockIdx.x * 256 + threadIdx.x;   // 0..32767
    if (t == 0) *ovf_n = 0;
    for (int i = t; i < n; i += 32768) cnt[i] = 0;
    int which = t >> 14;
    int idx = t & 16383;
    int k = idx & (D - 1);
    int c = idx >> 7;
    const float* W = which ? W2 : W1;
    _Float16* Wt = which ? Wt2 : Wt1;
    Wt[(size_t)c * D + k] = (_Float16)W[(size_t)k * D + c];
}

// ---------------- GEMM body (LDS-staged W) ----------------

// H[n x 128](f16) = X @ W via mfma_f32_16x16x32_f16.
// W tile (32KB) staged once per block into LDS with row stride WS=D+8:
//   b128 read bank-start = 4*((gl+q) mod 8) -> 8 lanes per 4-bank group ->
//   8-round b128 (the hardware floor), vs 16 rounds unpadded.
// A-fragments: 4 independent global loads hoisted before staging.
// Fused epilogue from fp32 accumulators: hs = H·a_src, hd = H·a_dst.
template<bool F16IN>
__device__ __forceinline__ void gemm_body(int bid, const void* __restrict__ Xv,
        const _Float16* __restrict__ Wt, const float* __restrict__ a_src,
        const float* __restrict__ a_dst, _Float16* __restrict__ H,
        float* __restrict__ hs, float* __restrict__ hd, int n,
        _Float16* wl) {
    const int lane = threadIdx.x & 63;
    const int wave = threadIdx.x >> 6;
    const int gl = lane & 15;
    const int q = lane >> 4;
    const int row0 = bid * 64 + wave * 16;

    int arow = row0 + gl;
    if (arow >= n) arow = n - 1;   // clamped load; stores are guarded below

    // A fragments first (independent of LDS staging)
    v8f16 afr[4];
    #pragma unroll
    for (int kc = 0; kc < 4; ++kc) {
        if constexpr (F16IN) {
            const _Float16* Xh = (const _Float16*)Xv;
            afr[kc] = *(const v8f16*)&Xh[(size_t)arow * D + kc * 32 + q * 8];
        } else {
            const float* p = &((const float*)Xv)[(size_t)arow * D + kc * 32 + q * 8];
            float4 x0 = *(const float4*)p;
            float4 x1 = *(const float4*)(p + 4);
            v8f16 t;
            t[0] = (_Float16)x0.x; t[1] = (_Float16)x0.y;
            t[2] = (_Float16)x0.z; t[3] = (_Float16)x0.w;
            t[4] = (_Float16)x1.x; t[5] = (_Float16)x1.y;
            t[6] = (_Float16)x1.z; t[7] = (_Float16)x1.w;
            afr[kc] = t;
        }
    }

    // stage W into LDS: 128 rows x 128 f16, 16 chunks of 8 f16 per row
    for (int i = threadIdx.x; i < D * D / 8; i += 256) {
        int r = i >> 4;
        int c = (i & 15) * 8;
        *(v8f16*)&wl[r * WS + c] = *(const v8f16*)&Wt[r * D + c];
    }
    __syncthreads();

    f32x4 acc[8];
    #pragma unroll
    for (int t = 0; t < 8; ++t) acc[t] = (f32x4){0.f, 0.f, 0.f, 0.f};

    #pragma unroll
    for (int kc = 0; kc < 4; ++kc) {
        #pragma unroll
        for (int t = 0; t < 8; ++t) {
            v8f16 bfr = *(const v8f16*)&wl[(t * 16 + gl) * WS + kc * 32 + q * 8];
            acc[t] = __builtin_amdgcn_mfma_f32_16x16x32_f16(afr[kc], bfr, acc[t], 0, 0, 0);
        }
    }

    float asv[8], adv[8];
    #pragma unroll
    for (int t = 0; t < 8; ++t) { asv[t] = a_src[t * 16 + gl]; adv[t] = a_dst[t * 16 + gl]; }

    // C/D layout: col = t*16 + (lane&15), row = row0 + q*4 + reg
    #pragma unroll
    for (int r = 0; r < 4; ++r) {
        int row = row0 + q * 4 + r;
        bool ok = row < n;
        float ps = 0.f, pd = 0.f;
        #pragma unroll
        for (int t = 0; t < 8; ++t) {
            float v = acc[t][r];
            ps = fmaf(v, asv[t], ps);
            pd = fmaf(v, adv[t], pd);
            if (ok) H[(size_t)row * D + t * 16 + gl] = (_Float16)v;
        }
        #pragma unroll
        for (int dlt = 8; dlt > 0; dlt >>= 1) {
            ps += __shfl_down(ps, dlt, 16);
            pd += __shfl_down(pd, dlt, 16);
        }
        if (ok && gl == 0) { hs[row] = ps; hd[row] = pd; }
    }
}

// ---------------- mega1: GEMM1 interleaved with rank-to-fixed-slot CSR ----------------
// Even blocks in [0, 2*gb) run GEMM, odd run rank; blocks >= 2*gb run rank, so
// both populations are co-resident from t=0 (requires eb >= gb, true here).

__global__ __launch_bounds__(256) void mega1_kernel(
        const float* __restrict__ x, const _Float16* __restrict__ Wt1,
        const float* __restrict__ a_src1, const float* __restrict__ a_dst1,
        _Float16* __restrict__ h, float* __restrict__ hs, float* __restrict__ hd,
        const int* __restrict__ ei, int* __restrict__ cnt, int* __restrict__ csr,
        int* __restrict__ ovf_n, int* __restrict__ ovf,
        int gb, int e_in, int n) {
    __shared__ _Float16 wl[D * WS];
    int b = blockIdx.x;
    int rid;
    if (b < 2 * gb) {
        if ((b & 1) == 0) {
            gemm_body<false>(b >> 1, x, Wt1, a_src1, a_dst1, h, hs, hd, n, wl);
            return;
        }
        rid = b >> 1;
    } else {
        rid = b - gb;
    }
    int e = rid * 256 + threadIdx.x;
    int tot = e_in + n;
    if (e >= tot) return;
    int s, d;
    if (e < e_in) { s = ei[e]; d = ei[e_in + e]; }
    else          { s = e - e_in; d = s; }
    int r = atomicAdd(&cnt[d], 1);
    if (r < SLOTS) {
        csr[d * SLOTS + r] = s;
    } else {
        int ix = atomicAdd(ovf_n, 1);
        if (ix < OVF_CAP) { ovf[2 * ix] = d; ovf[2 * ix + 1] = s; }
    }
}

__global__ __launch_bounds__(256) void gemm2_kernel(
        const _Float16* __restrict__ tb, const _Float16* __restrict__ Wt2,
        const float* __restrict__ a_src2, const float* __restrict__ a_dst2,
        _Float16* __restrict__ h, float* __restrict__ hs, float* __restrict__ hd,
        int n) {
    __shared__ _Float16 wl[D * WS];
    gemm_body<true>(blockIdx.x, tb, Wt2, a_src2, a_dst2, h, hs, hd, n, wl);
}

// ---------------- aggregate ----------------

__device__ __forceinline__ v2h pack_lo(uint a, uint b) {
    v2h r;
    r.x = __builtin_bit_cast(_Float16, (unsigned short)(a & 0xffffu));
    r.y = __builtin_bit_cast(_Float16, (unsigned short)(b & 0xffffu));
    return r;
}
__device__ __forceinline__ v2h pack_hi(uint a, uint b) {
    v2h r;
    r.x = __builtin_bit_cast(_Float16, (unsigned short)(a >> 16));
    r.y = __builtin_bit_cast(_Float16, (unsigned short)(b >> 16));
    return r;
}
__device__ __forceinline__ float lo_f(uint a) {
    return (float)__builtin_bit_cast(_Float16, (unsigned short)(a & 0xffffu));
}
__device__ __forceinline__ float hi_f(uint a) {
    return (float)__builtin_bit_cast(_Float16, (unsigned short)(a >> 16));
}

// Two nodes per 128-thread block, one wave per node; 24 slots in flight in a
// SINGLE trip (group grp=lane>>4 owns slots 6*grp..6*grp+5; gl=lane&15 owns
// 16B of the 256B f16 row). SLOTS=20 <= 24 so the slot path never loops.
// Inactive slots load the self-loop row (L2-resident, free) with w=0.
template<bool OUT_F16>
__global__ __launch_bounds__(128) void aggregate_kernel(
        const _Float16* __restrict__ h, const float* __restrict__ hs,
        const float* __restrict__ hd, const int* __restrict__ cnt,
        const int* __restrict__ csr, const int* __restrict__ ovf_n,
        const int* __restrict__ ovf, const float* __restrict__ bias,
        float* __restrict__ outf, _Float16* __restrict__ outb, int n) {
    int node = blockIdx.x * 2 + (threadIdx.x >> 6);
    if (node >= n) return;
    int lane = threadIdx.x & 63;
    int grp = lane >> 4;
    int gl = lane & 15;
    int deg = cnt[node];
    int mind = deg < SLOTS ? deg : SLOTS;
    const int base = node * SLOTS;
    float hdn = hd[node];
    const uint* hp = (const uint*)h;   // 2 f16 per uint, row stride 64 uints

    float acc[8] = {0.f, 0.f, 0.f, 0.f, 0.f, 0.f, 0.f, 0.f};
    float z = 0.f;

    int jb = 6 * grp;
    bool a[6];
    int s[6];
    #pragma unroll
    for (int u = 0; u < 6; ++u) {
        int idx = jb + u;
        a[u] = idx < mind;
        s[u] = a[u] ? csr[base + idx] : node;
    }
    uint4 r[6];
    #pragma unroll
    for (int u = 0; u < 6; ++u)
        r[u] = *(const uint4*)(hp + ((size_t)s[u] << 6) + (gl << 2));
    float w[6];
    #pragma unroll
    for (int u = 0; u < 6; ++u) {
        float e = hs[s[u]] + hdn;
        e = e > 0.f ? e : NEG_SLOPE * e;
        w[u] = a[u] ? __expf(e) : 0.f;
        z += w[u];
    }
#if __has_builtin(__builtin_amdgcn_fdot2)
    #pragma unroll
    for (int p = 0; p < 3; ++p) {
        v2h wp; wp.x = (_Float16)w[2 * p]; wp.y = (_Float16)w[2 * p + 1];
        const uint4& rA = r[2 * p];
        const uint4& rB = r[2 * p + 1];
        acc[0] = __builtin_amdgcn_fdot2(pack_lo(rA.x, rB.x), wp, acc[0], false);
        acc[1] = __builtin_amdgcn_fdot2(pack_hi(rA.x, rB.x), wp, acc[1], false);
        acc[2] = __builtin_amdgcn_fdot2(pack_lo(rA.y, rB.y), wp, acc[2], false);
        acc[3] = __builtin_amdgcn_fdot2(pack_hi(rA.y, rB.y), wp, acc[3], false);
        acc[4] = __builtin_amdgcn_fdot2(pack_lo(rA.z, rB.z), wp, acc[4], false);
        acc[5] = __builtin_amdgcn_fdot2(pack_hi(rA.z, rB.z), wp, acc[5], false);
        acc[6] = __builtin_amdgcn_fdot2(pack_lo(rA.w, rB.w), wp, acc[6], false);
        acc[7] = __builtin_amdgcn_fdot2(pack_hi(rA.w, rB.w), wp, acc[7], false);
    }
#else
    #pragma unroll
    for (int u = 0; u < 6; ++u) {
        acc[0] = fmaf(w[u], lo_f(r[u].x), acc[0]); acc[1] = fmaf(w[u], hi_f(r[u].x), acc[1]);
        acc[2] = fmaf(w[u], lo_f(r[u].y), acc[2]); acc[3] = fmaf(w[u], hi_f(r[u].y), acc[3]);
        acc[4] = fmaf(w[u], lo_f(r[u].z), acc[4]); acc[5] = fmaf(w[u], hi_f(r[u].z), acc[5]);
        acc[6] = fmaf(w[u], lo_f(r[u].w), acc[6]); acc[7] = fmaf(w[u], hi_f(r[u].w), acc[7]);
    }
#endif

    // rare: node overflowed its fixed slots -> scan the tiny overflow list
    if (deg > SLOTS) {
        int m = *ovf_n;
        if (m > OVF_CAP) m = OVF_CAP;
        for (int i = 0; i < m; ++i) {
            int od = ovf[2 * i];
            if (od == node) {
                int os = ovf[2 * i + 1];
                float e = hs[os] + hdn;
                e = e > 0.f ? e : NEG_SLOPE * e;
                float wv = __expf(e);
                if (grp == 0) {
                    uint4 rr = *(const uint4*)(hp + ((size_t)os << 6) + (gl << 2));
                    acc[0] = fmaf(wv, lo_f(rr.x), acc[0]); acc[1] = fmaf(wv, hi_f(rr.x), acc[1]);
                    acc[2] = fmaf(wv, lo_f(rr.y), acc[2]); acc[3] = fmaf(wv, hi_f(rr.y), acc[3]);
                    acc[4] = fmaf(wv, lo_f(rr.z), acc[4]); acc[5] = fmaf(wv, hi_f(rr.z), acc[5]);
                    acc[6] = fmaf(wv, lo_f(rr.w), acc[6]); acc[7] = fmaf(wv, hi_f(rr.w), acc[7]);
                    z += wv;
                }
            }
        }
    }

    // combine the 4 slot groups -> lanes 0..15 hold the full row
    #pragma unroll
    for (int dlt = 32; dlt >= 16; dlt >>= 1) {
        #pragma unroll
        for (int k = 0; k < 8; ++k) acc[k] += __shfl_down(acc[k], dlt, 64);
        z += __shfl_down(z, dlt, 64);
    }
    if (lane < 16) {
        float inv = 1.0f / z;   // self-loop guarantees z > 0
        float4 b0 = *(const float4*)&bias[lane * 8];
        float4 b1 = *(const float4*)&bias[lane * 8 + 4];
        float o[8];
        o[0] = acc[0] * inv + b0.x; o[1] = acc[1] * inv + b0.y;
        o[2] = acc[2] * inv + b0.z; o[3] = acc[3] * inv + b0.w;
        o[4] = acc[4] * inv + b1.x; o[5] = acc[5] * inv + b1.y;
        o[6] = acc[6] * inv + b1.z; o[7] = acc[7] * inv + b1.w;
        #pragma unroll
        for (int k = 0; k < 8; ++k) o[k] = o[k] > 0.f ? o[k] : 0.f;
        if constexpr (OUT_F16) {
            alignas(16) _Float16 ob[8];
            #pragma unroll
            for (int k = 0; k < 8; ++k) ob[k] = (_Float16)o[k];
            *(uint4*)&outb[(size_t)node * D + lane * 8] = *(const uint4*)ob;
        } else {
            float* op = outf + (size_t)node * D + lane * 8;
            *(float4*)op = make_float4(o[0], o[1], o[2], o[3]);
            *(float4*)(op + 4) = make_float4(o[4], o[5], o[6], o[7]);
        }
    }
}

// ---------------- Orchestration ----------------

extern "C" void kernel_launch(void* const* d_in, const int* in_sizes, int n_in,
                              void* d_out, int out_size, void* d_ws, size_t ws_size,
                              hipStream_t stream) {
    const float* x      = (const float*)d_in[0];
    const int*   ei     = (const int*)d_in[1];
    const float* W1     = (const float*)d_in[2];
    const float* a_src1 = (const float*)d_in[3];
    const float* a_dst1 = (const float*)d_in[4];
    const float* b1     = (const float*)d_in[5];
    const float* W2     = (const float*)d_in[6];
    const float* a_src2 = (const float*)d_in[7];
    const float* a_dst2 = (const float*)d_in[8];
    const float* b2     = (const float*)d_in[9];

    int n    = in_sizes[0] / D;       // 100000
    int e_in = in_sizes[1] / 2;       // 625000
    int e_tot = e_in + n;             // 725000

    // ws: h(f16) | Wt1 | Wt2 | hs | hd | cnt | ovf_n | ovf | csr  (~33 MB)
    _Float16* h   = (_Float16*)d_ws;
    _Float16* Wt1 = h + (size_t)n * D;
    _Float16* Wt2 = Wt1 + D * D;
    float* hs     = (float*)(Wt2 + D * D);
    float* hd     = hs + n;
    int*   cnt    = (int*)(hd + n);
    int*   ovf_n  = cnt + n;
    int*   ovf    = ovf_n + 1;
    int*   csr    = ovf + 2 * OVF_CAP;
    // layer-1 f16 output lives in d_out's first half (dead before agg2's fp32 write)
    _Float16* tb  = (_Float16*)d_out;

    int eb = (e_tot + 255) / 256;     // 2833
    int nb2 = (n + 1) / 2;
    int gb = (n + 63) / 64;           // 1563 (eb >= gb required by mega1 mapping)

    prep_kernel<<<128, 256, 0, stream>>>(W1, W2, Wt1, Wt2, cnt, ovf_n, n);
    mega1_kernel<<<gb + eb, 256, 0, stream>>>(x, Wt1, a_src1, a_dst1, h, hs, hd,
                                              ei, cnt, csr, ovf_n, ovf, gb, e_in, n);
    aggregate_kernel<true><<<nb2, 128, 0, stream>>>(h, hs, hd, cnt, csr, ovf_n, ovf,
                                                    b1, nullptr, tb, n);
    gemm2_kernel<<<gb, 256, 0, stream>>>(tb, Wt2, a_src2, a_dst2, h, hs, hd, n);
    aggregate_kernel<false><<<nb2, 128, 0, stream>>>(h, hs, hd, cnt, csr, ovf_n, ovf,
                                                     b2, (float*)d_out, nullptr, n);
}